// Round 1
// baseline (251.052 us; speedup 1.0000x reference)
//
#include <hip/hip_runtime.h>
#include <stdint.h>
#include <stddef.h>
#include <algorithm>

// GraphSAGE 2-layer, MI355X. RNG: JAX threefry partitionable (verified R1).
// R8: latency attack — counters showed nothing saturated (HBM 24%, VALU 17%,
// MFMA 4%) => latency-bound. VGPR was 64 with a 512 budget (LDS caps 16
// waves/CU at grid=4 blocks/CU). Spend registers on MLP:
//   1. neighbor-mean loop: 6 unconditional fully-unrolled rows/wave (+ tail),
//      all 10 loads issued per row before reduction (guards removed).
//   2. all 32 GEMM B-fragments preloaded into regs after gather issue;
//      GEMM loop is pure LDS+MFMA (static bf[kt][nt] indexing).
//   3. layer-2: 4 independent accumulators + unroll 8 (was one 256-deep
//      dependent FMA chain).

#define D       256
#define D4      64
#define BATCH   1024
#define F1      25
#define F2      10
#define MAXDEG  128
#define OUTD    128
#define SP      264          // S pitch in bf16 elements (528 B, 2-way free)
#define ZP      260          // Z pitch in bf16 elements

struct Perms { int p1[F1]; int p2[F2]; };

// ---------------- host-side threefry2x32 (JAX-exact, verified R1) ----------
static inline uint32_t rotl32(uint32_t x, int d){ return (x<<d)|(x>>(32-d)); }

static void tf2x32(uint32_t k0, uint32_t k1, uint32_t x0, uint32_t x1,
                   uint32_t* o0, uint32_t* o1){
  uint32_t ks0=k0, ks1=k1, ks2 = k0^k1^0x1BD11BDAu;
  static const int rot[2][4] = {{13,15,26,6},{17,29,16,24}};
  x0 += ks0; x1 += ks1;
  for (int g=0; g<5; ++g){
    const int* r = rot[g&1];
    for (int i=0;i<4;++i){ x0 += x1; x1 = rotl32(x1, r[i]) ^ x0; }
    switch(g){
      case 0: x0 += ks1; x1 += ks2 + 1u; break;
      case 1: x0 += ks2; x1 += ks0 + 2u; break;
      case 2: x0 += ks0; x1 += ks1 + 3u; break;
      case 3: x0 += ks1; x1 += ks2 + 4u; break;
      default:x0 += ks2; x1 += ks0 + 5u; break;
    }
  }
  *o0 = x0; *o1 = x1;
}

static void mkperm(uint32_t ka, uint32_t kb, int n, int* outp){
  uint32_t ska, skb;
  tf2x32(ka, kb, 0u, 1u, &ska, &skb);
  uint32_t bits[MAXDEG];
  int idxs[MAXDEG];
  for (int i=0;i<MAXDEG;++i){
    uint32_t y0,y1; tf2x32(ska,skb, 0u,(uint32_t)i, &y0,&y1);
    bits[i] = y0 ^ y1;
    idxs[i] = i;
  }
  std::stable_sort(idxs, idxs+MAXDEG,
                   [&](int a,int b){ return bits[a] < bits[b]; });
  for (int j=0;j<n;++j) outp[j] = idxs[j];
}

static void compute_perms(Perms& P){
  uint32_t k1a,k1b,k2a,k2b;
  tf2x32(0u,42u, 0u,0u, &k1a,&k1b);
  tf2x32(0u,42u, 0u,1u, &k2a,&k2b);
  mkperm(k1a,k1b, F1, P.p1);
  mkperm(k2a,k2b, F2, P.p2);
}

// ---------------- device helpers ----------------
typedef short s16x8 __attribute__((ext_vector_type(8)));
typedef float f32x4 __attribute__((ext_vector_type(4)));

__device__ __forceinline__ uint16_t f2bf(float f){
  uint32_t u = __float_as_uint(f);
  u += 0x7fffu + ((u >> 16) & 1u);      // RNE
  return (uint16_t)(u >> 16);
}
__device__ __forceinline__ float bf2f(uint16_t h){
  return __uint_as_float(((uint32_t)h) << 16);
}

// ---------------- merged pack kernel ---------------------------------------
// g < 8192: W1 bf16 fragment groups: g = (kt*16 + ct)*64 + lane ->
//   W[n=ct*16+(lane&15)][k=kt*32+(lane>>4)*8 ..+8]   n<128 -> W1x else W1n
// g >= 8192: W2T[k*256+o] fp32 transpose.
__global__ __launch_bounds__(256) void pack_k(
    const float* __restrict__ W1x, const float* __restrict__ W1n,
    const float* __restrict__ W2x, const float* __restrict__ W2n,
    uint16_t* __restrict__ WB, float* __restrict__ W2T){
  int g = blockIdx.x*256 + threadIdx.x;
  if (g < 8192){
    int kt = g >> 10, ct = (g >> 6) & 15, lane = g & 63;
    int n = ct*16 + (lane & 15);
    int k = kt*32 + (lane >> 4)*8;
    const float* src = (n < OUTD) ? (W1x + (size_t)n*D + k)
                                  : (W1n + (size_t)(n-OUTD)*D + k);
    float4 f0 = *(const float4*)src;
    float4 f1 = *(const float4*)(src + 4);
    uint32_t p[4] = {
      (uint32_t)f2bf(f0.x) | ((uint32_t)f2bf(f0.y)<<16),
      (uint32_t)f2bf(f0.z) | ((uint32_t)f2bf(f0.w)<<16),
      (uint32_t)f2bf(f1.x) | ((uint32_t)f2bf(f1.y)<<16),
      (uint32_t)f2bf(f1.z) | ((uint32_t)f2bf(f1.w)<<16) };
    *(uint4*)(WB + (size_t)g*8) = *(uint4*)p;
  } else {
    int idx = g - 8192;                       // 65536
    int k = idx >> 8, o = idx & 255;
    W2T[idx] = (o < OUTD) ? W2x[(size_t)o*D + k]
                          : W2n[(size_t)(o-OUTD)*D + k];
  }
}

// ---------------- fused mega kernel ----------------------------------------
// One block per batch element b:
//  sids[0..24]=adj[ids[b],p1], sids[25]=ids[b]; nidx[250]=adj[sids[j],p2[u]]
//  S rows 0..25 = bf16(feats[sids]); rows 26..50 = bf16(mean_u feats[nidx]);
//  row 51 = M0 = colmean(rows 0..24); rows 52..63 junk (discarded outputs).
//  Dm = S @ [W1x|W1n]^T (MFMA 16x16x32, B-frags preloaded in VGPRs)
//  Z (aliases S) r<26 = relu(Dm[r][0:128] | Dm[26+r][128:256] + b1); z0 fp32.
//  M2 = colmean(Z[0:25]); out[b] = [z0@W2x^T+b2x | M2@W2n^T+b2n].
__global__ __launch_bounds__(256, 4) void mega7_k(
    const float4* __restrict__ feats4,
    const int* __restrict__ ids, const int* __restrict__ adj,
    const uint16_t* __restrict__ WB, const float* __restrict__ W2T,
    const float* __restrict__ b1x, const float* __restrict__ b1n,
    const float* __restrict__ b2x, const float* __restrict__ b2n,
    float* __restrict__ out, Perms P)
{
  __shared__ uint16_t S[64*SP];        // 33.8 KB; Z aliases this after GEMM
  __shared__ float    M2s[D];          // 1 KB
  __shared__ float    Z0s[D];          // 1 KB
  __shared__ int      sids[26];
  __shared__ int      nidx[F1*F2];     // 1 KB

  const int b    = blockIdx.x;
  const int tid  = threadIdx.x;
  const int lane = tid & 63;
  const int w    = tid >> 6;
  const int ln   = lane & 15;
  const int q    = lane >> 4;
  const int id   = ids[b];
  uint16_t* Z = S;                     // ZP-pitch view, rows 0..25

  // -- sampling --
  if (tid < F1) sids[tid] = adj[(size_t)id*MAXDEG + P.p1[tid]];
  if (tid == F1) sids[F1] = id;
  __syncthreads();
  if (tid < F1*F2){
    int j = tid / F2, u = tid - (tid/F2)*F2;
    nidx[tid] = adj[(size_t)sids[j]*MAXDEG + P.p2[u]];
  }
  __syncthreads();

  // -- gather phase --
  // self-row loads batched first (complete during the neighbor loop)
  float4 va[7];
  #pragma unroll
  for (int l=0;l<7;++l){
    int idx = tid + l*256;
    if (idx < 26*D4)
      va[l] = feats4[(size_t)sids[idx>>6]*D4 + (idx&63)];
  }

  // neighbor means: wave w owns rows j = w, w+4, ... ; lane owns float4 col.
  // 6 UNCONDITIONAL rows fully unrolled (max j = 3+20 = 23 < 25) so the
  // compiler can hoist loads across rows; guarded tail row 24 for w==0.
  #pragma unroll
  for (int t=0;t<6;++t){
    const int j = w + 4*t;
    const int* np = &nidx[j*F2];
    float4 v[F2];
    #pragma unroll
    for (int u=0;u<F2;++u)
      v[u] = feats4[(size_t)np[u]*D4 + lane];
    float4 s = v[0];
    #pragma unroll
    for (int u=1;u<F2;++u){
      s.x+=v[u].x; s.y+=v[u].y; s.z+=v[u].z; s.w+=v[u].w;
    }
    const float inv = 1.f/F2;
    uint32_t p[2] = {
      (uint32_t)f2bf(s.x*inv) | ((uint32_t)f2bf(s.y*inv)<<16),
      (uint32_t)f2bf(s.z*inv) | ((uint32_t)f2bf(s.w*inv)<<16) };
    *(uint2*)(S + (26+j)*SP + lane*4) = *(uint2*)p;
  }
  if (w == 0){
    const int j = 24;
    const int* np = &nidx[j*F2];
    float4 v[F2];
    #pragma unroll
    for (int u=0;u<F2;++u)
      v[u] = feats4[(size_t)np[u]*D4 + lane];
    float4 s = v[0];
    #pragma unroll
    for (int u=1;u<F2;++u){
      s.x+=v[u].x; s.y+=v[u].y; s.z+=v[u].z; s.w+=v[u].w;
    }
    const float inv = 1.f/F2;
    uint32_t p[2] = {
      (uint32_t)f2bf(s.x*inv) | ((uint32_t)f2bf(s.y*inv)<<16),
      (uint32_t)f2bf(s.z*inv) | ((uint32_t)f2bf(s.w*inv)<<16) };
    *(uint2*)(S + (26+j)*SP + lane*4) = *(uint2*)p;
  }

  // preload ALL GEMM B-fragments (32 x s16x8 = 128 VGPRs); these L2-hit
  // loads complete under the self-store + M0 phases below.
  s16x8 bf[8][4];
  #pragma unroll
  for (int kt=0;kt<8;++kt)
    #pragma unroll
    for (int nt=0;nt<4;++nt)
      bf[kt][nt] = *(const s16x8*)(WB + (size_t)((kt*16 + w*4 + nt)*64 + lane)*8);

  // store self rows
  #pragma unroll
  for (int l=0;l<7;++l){
    int idx = tid + l*256;
    if (idx < 26*D4){
      int r = idx>>6, c4 = idx&63;
      uint32_t p[2] = { (uint32_t)f2bf(va[l].x) | ((uint32_t)f2bf(va[l].y)<<16),
                        (uint32_t)f2bf(va[l].z) | ((uint32_t)f2bf(va[l].w)<<16) };
      *(uint2*)(S + r*SP + c4*4) = *(uint2*)p;
    }
  }
  __syncthreads();

  // M0 -> S row 51
  {
    float s = 0.f;
    #pragma unroll
    for (int r=0;r<F1;++r) s += bf2f(S[r*SP + tid]);
    S[51*SP + tid] = f2bf(s * (1.f/F1));
  }
  __syncthreads();

  // -- layer-1 MFMA GEMM: 8 k-tiles of 32, barrier-free, B from regs --
  f32x4 acc[4][4];
  #pragma unroll
  for (int mt=0;mt<4;++mt)
    #pragma unroll
    for (int nt=0;nt<4;++nt) acc[mt][nt] = (f32x4){0.f,0.f,0.f,0.f};

  #pragma unroll
  for (int kt = 0; kt < 8; ++kt){
    s16x8 af[4];
    #pragma unroll
    for (int mt=0;mt<4;++mt)
      af[mt] = *(const s16x8*)(S + (mt*16 + ln)*SP + kt*32 + q*8);
    #pragma unroll
    for (int mt=0;mt<4;++mt)
      #pragma unroll
      for (int nt=0;nt<4;++nt)
        acc[mt][nt] = __builtin_amdgcn_mfma_f32_16x16x32_bf16(
                        af[mt], bf[kt][nt], acc[mt][nt], 0, 0, 0);
  }
  __syncthreads();   // all S reads done before Z (alias) writes

  // -- epilogue: bias + relu -> Z (bf16) + fp32 z0 capture --
  {
    const bool left = (w < 2);
    float bia[4];
    #pragma unroll
    for (int nt=0;nt<4;++nt){
      int n = w*64 + nt*16 + ln;
      bia[nt] = left ? b1x[n] : b1n[n-OUTD];
    }
    #pragma unroll
    for (int mt=0;mt<4;++mt)
      #pragma unroll
      for (int nt=0;nt<4;++nt){
        int n = w*64 + nt*16 + ln;
        #pragma unroll
        for (int reg=0;reg<4;++reg){
          int m = mt*16 + q*4 + reg;
          float val = fmaxf(acc[mt][nt][reg] + bia[nt], 0.f);
          if (left){
            if (m < 26) Z[m*ZP + n] = f2bf(val);
            if (m == 25) Z0s[n] = val;
          } else {
            if (m >= 26 && m < 52) Z[(m-26)*ZP + n] = f2bf(val);
            if (m == 51) Z0s[n] = val;
          }
        }
      }
  }
  __syncthreads();

  // M2 = colmean(Z rows 0..24)
  {
    float s = 0.f;
    #pragma unroll
    for (int r=0;r<F1;++r) s += bf2f(Z[r*ZP + tid]);
    M2s[tid] = s * (1.f/F1);
  }
  __syncthreads();

  // -- layer 2: fp32, W2T coalesced, 4 independent accumulator chains --
  {
    const int o = tid;
    const float* zsrc = (o < OUTD) ? Z0s : M2s;   // wave-uniform select
    float a0=0.f, a1=0.f, a2=0.f, a3=0.f;
    #pragma unroll 8
    for (int k4=0;k4<D4;++k4){
      float4 z = *(const float4*)(zsrc + k4*4);
      const float* wp = W2T + (size_t)k4*4*D + o;
      a0 += z.x * wp[0];
      a1 += z.y * wp[D];
      a2 += z.z * wp[2*D];
      a3 += z.w * wp[3*D];
    }
    float acc2 = (a0 + a2) + (a1 + a3);
    acc2 += (o < OUTD) ? b2x[o] : b2n[o-OUTD];
    out[(size_t)b*D + o] = acc2;
  }
}

// ---------------- launch ----------------
extern "C" void kernel_launch(void* const* d_in, const int* in_sizes, int n_in,
                              void* d_out, int out_size, void* d_ws, size_t ws_size,
                              hipStream_t stream){
  const int*   ids   = (const int*)  d_in[0];
  const int*   adj   = (const int*)  d_in[1];
  const float* feats = (const float*)d_in[2];
  const float* W1x   = (const float*)d_in[3];
  const float* b1x   = (const float*)d_in[4];
  const float* W1n   = (const float*)d_in[5];
  const float* b1n   = (const float*)d_in[6];
  const float* W2x   = (const float*)d_in[7];
  const float* b2x   = (const float*)d_in[8];
  const float* W2n   = (const float*)d_in[9];
  const float* b2n   = (const float*)d_in[10];
  float* out = (float*)d_out;

  Perms P;
  compute_perms(P);

  char* wsb = (char*)d_ws;
  uint16_t* WB  = (uint16_t*)wsb;                    // 131 KB
  wsb += (size_t)8192*8*sizeof(uint16_t);
  float*    W2T = (float*)wsb;                       // 256 KB

  hipLaunchKernelGGL(pack_k, dim3(288), dim3(256), 0, stream,
                     W1x, W1n, W2x, W2n, WB, W2T);
  hipLaunchKernelGGL(mega7_k, dim3(BATCH), dim3(256), 0, stream,
                     (const float4*)feats, ids, adj, WB, W2T,
                     b1x, b1n, b2x, b2n, out, P);
}

// Round 3
// 225.385 us; speedup vs baseline: 1.1139x; 1.1139x over previous
//
#include <hip/hip_runtime.h>
#include <stdint.h>
#include <stddef.h>
#include <algorithm>

// GraphSAGE 2-layer, MI355X. RNG: JAX threefry partitionable (verified R1).
// R10 = R9 resubmit (R9 bench was an infra failure: container acquisition
// failed twice; kernel never ran). Rationale unchanged:
// R8's bf[8][4] preload (128 VGPRs) blew the 128-VGPR cap from
// __launch_bounds__(256,4) -> 84 MB scratch writes, dur 77.7->100us. But R8
// proved the memory system delivers 2.7 TB/s when offered more in-flight
// traffic => latency/MLP-bound, not service-rate-bound. Keep the cheap MLP
// levers:
//   - neighbor-mean loop: 6 unconditional fully-unrolled rows/wave (+ tail),
//     all 10 loads issued per row before reduction (deep load pipelining).
//   - layer-2: 4 independent accumulator chains.
// GEMM uses per-kt B-fragment loads from WB (L1/L2-hot, GEMM ~0.5us).

#define D       256
#define D4      64
#define BATCH   1024
#define F1      25
#define F2      10
#define MAXDEG  128
#define OUTD    128
#define SP      264          // S pitch in bf16 elements (528 B, 2-way free)
#define ZP      260          // Z pitch in bf16 elements

struct Perms { int p1[F1]; int p2[F2]; };

// ---------------- host-side threefry2x32 (JAX-exact, verified R1) ----------
static inline uint32_t rotl32(uint32_t x, int d){ return (x<<d)|(x>>(32-d)); }

static void tf2x32(uint32_t k0, uint32_t k1, uint32_t x0, uint32_t x1,
                   uint32_t* o0, uint32_t* o1){
  uint32_t ks0=k0, ks1=k1, ks2 = k0^k1^0x1BD11BDAu;
  static const int rot[2][4] = {{13,15,26,6},{17,29,16,24}};
  x0 += ks0; x1 += ks1;
  for (int g=0; g<5; ++g){
    const int* r = rot[g&1];
    for (int i=0;i<4;++i){ x0 += x1; x1 = rotl32(x1, r[i]) ^ x0; }
    switch(g){
      case 0: x0 += ks1; x1 += ks2 + 1u; break;
      case 1: x0 += ks2; x1 += ks0 + 2u; break;
      case 2: x0 += ks0; x1 += ks1 + 3u; break;
      case 3: x0 += ks1; x1 += ks2 + 4u; break;
      default:x0 += ks2; x1 += ks0 + 5u; break;
    }
  }
  *o0 = x0; *o1 = x1;
}

static void mkperm(uint32_t ka, uint32_t kb, int n, int* outp){
  uint32_t ska, skb;
  tf2x32(ka, kb, 0u, 1u, &ska, &skb);
  uint32_t bits[MAXDEG];
  int idxs[MAXDEG];
  for (int i=0;i<MAXDEG;++i){
    uint32_t y0,y1; tf2x32(ska,skb, 0u,(uint32_t)i, &y0,&y1);
    bits[i] = y0 ^ y1;
    idxs[i] = i;
  }
  std::stable_sort(idxs, idxs+MAXDEG,
                   [&](int a,int b){ return bits[a] < bits[b]; });
  for (int j=0;j<n;++j) outp[j] = idxs[j];
}

static void compute_perms(Perms& P){
  uint32_t k1a,k1b,k2a,k2b;
  tf2x32(0u,42u, 0u,0u, &k1a,&k1b);
  tf2x32(0u,42u, 0u,1u, &k2a,&k2b);
  mkperm(k1a,k1b, F1, P.p1);
  mkperm(k2a,k2b, F2, P.p2);
}

// ---------------- device helpers ----------------
typedef short s16x8 __attribute__((ext_vector_type(8)));
typedef float f32x4 __attribute__((ext_vector_type(4)));

__device__ __forceinline__ uint16_t f2bf(float f){
  uint32_t u = __float_as_uint(f);
  u += 0x7fffu + ((u >> 16) & 1u);      // RNE
  return (uint16_t)(u >> 16);
}
__device__ __forceinline__ float bf2f(uint16_t h){
  return __uint_as_float(((uint32_t)h) << 16);
}

// ---------------- merged pack kernel ---------------------------------------
// g < 8192: W1 bf16 fragment groups: g = (kt*16 + ct)*64 + lane ->
//   W[n=ct*16+(lane&15)][k=kt*32+(lane>>4)*8 ..+8]   n<128 -> W1x else W1n
// g >= 8192: W2T[k*256+o] fp32 transpose.
__global__ __launch_bounds__(256) void pack_k(
    const float* __restrict__ W1x, const float* __restrict__ W1n,
    const float* __restrict__ W2x, const float* __restrict__ W2n,
    uint16_t* __restrict__ WB, float* __restrict__ W2T){
  int g = blockIdx.x*256 + threadIdx.x;
  if (g < 8192){
    int kt = g >> 10, ct = (g >> 6) & 15, lane = g & 63;
    int n = ct*16 + (lane & 15);
    int k = kt*32 + (lane >> 4)*8;
    const float* src = (n < OUTD) ? (W1x + (size_t)n*D + k)
                                  : (W1n + (size_t)(n-OUTD)*D + k);
    float4 f0 = *(const float4*)src;
    float4 f1 = *(const float4*)(src + 4);
    uint32_t p[4] = {
      (uint32_t)f2bf(f0.x) | ((uint32_t)f2bf(f0.y)<<16),
      (uint32_t)f2bf(f0.z) | ((uint32_t)f2bf(f0.w)<<16),
      (uint32_t)f2bf(f1.x) | ((uint32_t)f2bf(f1.y)<<16),
      (uint32_t)f2bf(f1.z) | ((uint32_t)f2bf(f1.w)<<16) };
    *(uint4*)(WB + (size_t)g*8) = *(uint4*)p;
  } else {
    int idx = g - 8192;                       // 65536
    int k = idx >> 8, o = idx & 255;
    W2T[idx] = (o < OUTD) ? W2x[(size_t)o*D + k]
                          : W2n[(size_t)(o-OUTD)*D + k];
  }
}

// ---------------- fused mega kernel ----------------------------------------
// One block per batch element b:
//  sids[0..24]=adj[ids[b],p1], sids[25]=ids[b]; nidx[250]=adj[sids[j],p2[u]]
//  S rows 0..25 = bf16(feats[sids]); rows 26..50 = bf16(mean_u feats[nidx]);
//  row 51 = M0 = colmean(rows 0..24); rows 52..63 junk (discarded outputs).
//  Dm = S @ [W1x|W1n]^T (MFMA 16x16x32, B-frags from global WB, barrier-free)
//  Z (aliases S) r<26 = relu(Dm[r][0:128] | Dm[26+r][128:256] + b1); z0 fp32.
//  M2 = colmean(Z[0:25]); out[b] = [z0@W2x^T+b2x | M2@W2n^T+b2n].
__global__ __launch_bounds__(256, 4) void mega8_k(
    const float4* __restrict__ feats4,
    const int* __restrict__ ids, const int* __restrict__ adj,
    const uint16_t* __restrict__ WB, const float* __restrict__ W2T,
    const float* __restrict__ b1x, const float* __restrict__ b1n,
    const float* __restrict__ b2x, const float* __restrict__ b2n,
    float* __restrict__ out, Perms P)
{
  __shared__ uint16_t S[64*SP];        // 33.8 KB; Z aliases this after GEMM
  __shared__ float    M2s[D];          // 1 KB
  __shared__ float    Z0s[D];          // 1 KB
  __shared__ int      sids[26];
  __shared__ int      nidx[F1*F2];     // 1 KB

  const int b    = blockIdx.x;
  const int tid  = threadIdx.x;
  const int lane = tid & 63;
  const int w    = tid >> 6;
  const int ln   = lane & 15;
  const int q    = lane >> 4;
  const int id   = ids[b];
  uint16_t* Z = S;                     // ZP-pitch view, rows 0..25

  // -- sampling --
  if (tid < F1) sids[tid] = adj[(size_t)id*MAXDEG + P.p1[tid]];
  if (tid == F1) sids[F1] = id;
  __syncthreads();
  if (tid < F1*F2){
    int j = tid / F2, u = tid - (tid/F2)*F2;
    nidx[tid] = adj[(size_t)sids[j]*MAXDEG + P.p2[u]];
  }
  __syncthreads();

  // -- gather phase --
  // self-row loads batched first (complete during the neighbor loop)
  float4 va[7];
  #pragma unroll
  for (int l=0;l<7;++l){
    int idx = tid + l*256;
    if (idx < 26*D4)
      va[l] = feats4[(size_t)sids[idx>>6]*D4 + (idx&63)];
  }

  // neighbor means: wave w owns rows j = w, w+4, ... ; lane owns float4 col.
  // 6 UNCONDITIONAL rows fully unrolled (max j = 3+20 = 23 < 25) so the
  // compiler can hoist loads across rows; guarded tail row 24 for w==0.
  #pragma unroll
  for (int t=0;t<6;++t){
    const int j = w + 4*t;
    const int* np = &nidx[j*F2];
    float4 v[F2];
    #pragma unroll
    for (int u=0;u<F2;++u)
      v[u] = feats4[(size_t)np[u]*D4 + lane];
    float4 s = v[0];
    #pragma unroll
    for (int u=1;u<F2;++u){
      s.x+=v[u].x; s.y+=v[u].y; s.z+=v[u].z; s.w+=v[u].w;
    }
    const float inv = 1.f/F2;
    uint32_t p[2] = {
      (uint32_t)f2bf(s.x*inv) | ((uint32_t)f2bf(s.y*inv)<<16),
      (uint32_t)f2bf(s.z*inv) | ((uint32_t)f2bf(s.w*inv)<<16) };
    *(uint2*)(S + (26+j)*SP + lane*4) = *(uint2*)p;
  }
  if (w == 0){
    const int j = 24;
    const int* np = &nidx[j*F2];
    float4 v[F2];
    #pragma unroll
    for (int u=0;u<F2;++u)
      v[u] = feats4[(size_t)np[u]*D4 + lane];
    float4 s = v[0];
    #pragma unroll
    for (int u=1;u<F2;++u){
      s.x+=v[u].x; s.y+=v[u].y; s.z+=v[u].z; s.w+=v[u].w;
    }
    const float inv = 1.f/F2;
    uint32_t p[2] = {
      (uint32_t)f2bf(s.x*inv) | ((uint32_t)f2bf(s.y*inv)<<16),
      (uint32_t)f2bf(s.z*inv) | ((uint32_t)f2bf(s.w*inv)<<16) };
    *(uint2*)(S + (26+j)*SP + lane*4) = *(uint2*)p;
  }

  // store self rows
  #pragma unroll
  for (int l=0;l<7;++l){
    int idx = tid + l*256;
    if (idx < 26*D4){
      int r = idx>>6, c4 = idx&63;
      uint32_t p[2] = { (uint32_t)f2bf(va[l].x) | ((uint32_t)f2bf(va[l].y)<<16),
                        (uint32_t)f2bf(va[l].z) | ((uint32_t)f2bf(va[l].w)<<16) };
      *(uint2*)(S + r*SP + c4*4) = *(uint2*)p;
    }
  }
  __syncthreads();

  // M0 -> S row 51
  {
    float s = 0.f;
    #pragma unroll
    for (int r=0;r<F1;++r) s += bf2f(S[r*SP + tid]);
    S[51*SP + tid] = f2bf(s * (1.f/F1));
  }
  __syncthreads();

  // -- layer-1 MFMA GEMM: 8 k-tiles of 32, barrier-free --
  f32x4 acc[4][4];
  #pragma unroll
  for (int mt=0;mt<4;++mt)
    #pragma unroll
    for (int nt=0;nt<4;++nt) acc[mt][nt] = (f32x4){0.f,0.f,0.f,0.f};

  #pragma unroll 2
  for (int kt = 0; kt < 8; ++kt){
    s16x8 af[4], bfk[4];
    #pragma unroll
    for (int mt=0;mt<4;++mt)
      af[mt] = *(const s16x8*)(S + (mt*16 + ln)*SP + kt*32 + q*8);
    #pragma unroll
    for (int nt=0;nt<4;++nt)
      bfk[nt] = *(const s16x8*)(WB + (size_t)((kt*16 + w*4 + nt)*64 + lane)*8);
    #pragma unroll
    for (int mt=0;mt<4;++mt)
      #pragma unroll
      for (int nt=0;nt<4;++nt)
        acc[mt][nt] = __builtin_amdgcn_mfma_f32_16x16x32_bf16(
                        af[mt], bfk[nt], acc[mt][nt], 0, 0, 0);
  }
  __syncthreads();   // all S reads done before Z (alias) writes

  // -- epilogue: bias + relu -> Z (bf16) + fp32 z0 capture --
  {
    const bool left = (w < 2);
    float bia[4];
    #pragma unroll
    for (int nt=0;nt<4;++nt){
      int n = w*64 + nt*16 + ln;
      bia[nt] = left ? b1x[n] : b1n[n-OUTD];
    }
    #pragma unroll
    for (int mt=0;mt<4;++mt)
      #pragma unroll
      for (int nt=0;nt<4;++nt){
        int n = w*64 + nt*16 + ln;
        #pragma unroll
        for (int reg=0;reg<4;++reg){
          int m = mt*16 + q*4 + reg;
          float val = fmaxf(acc[mt][nt][reg] + bia[nt], 0.f);
          if (left){
            if (m < 26) Z[m*ZP + n] = f2bf(val);
            if (m == 25) Z0s[n] = val;
          } else {
            if (m >= 26 && m < 52) Z[(m-26)*ZP + n] = f2bf(val);
            if (m == 51) Z0s[n] = val;
          }
        }
      }
  }
  __syncthreads();

  // M2 = colmean(Z rows 0..24)
  {
    float s = 0.f;
    #pragma unroll
    for (int r=0;r<F1;++r) s += bf2f(Z[r*ZP + tid]);
    M2s[tid] = s * (1.f/F1);
  }
  __syncthreads();

  // -- layer 2: fp32, W2T coalesced, 4 independent accumulator chains --
  {
    const int o = tid;
    const float* zsrc = (o < OUTD) ? Z0s : M2s;   // wave-uniform select
    float a0=0.f, a1=0.f, a2=0.f, a3=0.f;
    #pragma unroll 8
    for (int k4=0;k4<D4;++k4){
      float4 z = *(const float4*)(zsrc + k4*4);
      const float* wp = W2T + (size_t)k4*4*D + o;
      a0 += z.x * wp[0];
      a1 += z.y * wp[D];
      a2 += z.z * wp[2*D];
      a3 += z.w * wp[3*D];
    }
    float acc2 = (a0 + a2) + (a1 + a3);
    acc2 += (o < OUTD) ? b2x[o] : b2n[o-OUTD];
    out[(size_t)b*D + o] = acc2;
  }
}

// ---------------- launch ----------------
extern "C" void kernel_launch(void* const* d_in, const int* in_sizes, int n_in,
                              void* d_out, int out_size, void* d_ws, size_t ws_size,
                              hipStream_t stream){
  const int*   ids   = (const int*)  d_in[0];
  const int*   adj   = (const int*)  d_in[1];
  const float* feats = (const float*)d_in[2];
  const float* W1x   = (const float*)d_in[3];
  const float* b1x   = (const float*)d_in[4];
  const float* W1n   = (const float*)d_in[5];
  const float* b1n   = (const float*)d_in[6];
  const float* W2x   = (const float*)d_in[7];
  const float* b2x   = (const float*)d_in[8];
  const float* W2n   = (const float*)d_in[9];
  const float* b2n   = (const float*)d_in[10];
  float* out = (float*)d_out;

  Perms P;
  compute_perms(P);

  char* wsb = (char*)d_ws;
  uint16_t* WB  = (uint16_t*)wsb;                    // 131 KB
  wsb += (size_t)8192*8*sizeof(uint16_t);
  float*    W2T = (float*)wsb;                       // 256 KB

  hipLaunchKernelGGL(pack_k, dim3(288), dim3(256), 0, stream,
                     W1x, W1n, W2x, W2n, WB, W2T);
  hipLaunchKernelGGL(mega8_k, dim3(BATCH), dim3(256), 0, stream,
                     (const float4*)feats, ids, adj, WB, W2T,
                     b1x, b1n, b2x, b2n, out, P);
}